// Round 2
// baseline (84.602 us; speedup 1.0000x reference)
//
#include <hip/hip_runtime.h>
#include <hip/hip_bf16.h>
#include <math.h>

#define N_AUDIO 32768
#define NB 8
#define NC 128
#define NT 128
#define NO 128

// ws layout:
//   SEG : float4[NB][NT][NO]  (f/2, df/1024, a/128, da/128)  = 2 MiB
//   CW  : float [NB][NT][NO]  ((C_i/2) mod 1, revolutions)   = 512 KiB
// z_rev(m) = CW + m*(f/2) + m^2*(df/1024); audio = sum_o amp'(m)*sin(2*pi*fract(z_rev))

__global__ __launch_bounds__(128)
void prep_kernel(const float* __restrict__ x,
                 const float* __restrict__ amp_w,
                 const float* __restrict__ amp_b,
                 const float* __restrict__ freq_w,
                 const float* __restrict__ freq_b,
                 float4* __restrict__ SEG,
                 float*  __restrict__ CW)
{
    const int bo = blockIdx.x;            // 0..1023
    const int b  = bo >> 7;
    const int o  = bo & 127;
    const int t  = threadIdx.x;           // knot index 0..127

    const float* xp = x + b * (NC * NT) + t;   // x[b, c, t], stride NT per c
    const float* wa = amp_w  + o * NC;
    const float* wf = freq_w + o * NC;

    float va = 0.f, vf = 0.f;
#pragma unroll 8
    for (int c = 0; c < NC; ++c) {
        float xv = xp[c * NT];
        va = fmaf(xv, wa[c], va);
        vf = fmaf(xv, wf[c], vf);
    }
    va += amp_b[o];
    vf += freq_b[o];
    const float sa = 1.f / (1.f + __expf(-va));   // amp knot
    const float sf = 1.f / (1.f + __expf(-vf));   // freq knot

    __shared__ float  fsh[NT];
    __shared__ float  ash[NT];
    __shared__ double psh[NT];
    fsh[t] = sf;
    ash[t] = sa;
    psh[t] = (double)sf;
    __syncthreads();

    // Hillis-Steele inclusive scan (double) over the 128 freq knots
    for (int off = 1; off < NT; off <<= 1) {
        double add = (t >= off) ? psh[t - off] : 0.0;
        double v   = psh[t];
        __syncthreads();
        psh[t] = v + add;
        __syncthreads();
    }
    const double incl = psh[t];
    const double excl = incl - (double)sf;
    // C_i (rev) = 128 * sum_{s<i} f_s + 64 * f_i  (phase/2pi at segment start)
    double Cd = 128.0 * excl + 64.0 * (double)sf;
    Cd -= floor(Cd);                      // mod 1 revolution

    const float df = (t < NT - 1) ? (fsh[t + 1] - sf) : 0.f;
    const float da = (t < NT - 1) ? (ash[t + 1] - sa) : 0.f;

    const int idx = (b * NT + t) * NO + o;   // [b][i][o] layout
    SEG[idx] = make_float4(0.5f * sf,              // m coefficient (rev)
                           df * (1.f / 1024.f),    // m^2 coefficient (rev)
                           sa * (1.f / 128.f),     // amp / 128 (mean folded in)
                           da * (1.f / 128.f));    // damp / 128
    CW[idx]  = (float)Cd;
}

// Each block: one 128-sample chunk of one batch, exactly one segment row.
// row/base are derived ONLY from blockIdx -> formally uniform -> the
// per-oscillator coefficient loads scalarize to s_load (SMEM/K$), freeing
// the DS pipe entirely (old version: ~192 broadcast ds_read insts/wave).
//
// Chunk math (exact algebra of the old k/h scheme):
//   c == 0        : head, row 0, mask 0, m = tid-127   (z = (j+1)*f0/2)
//   c odd  (>=1)  : row (c-1)/2, m = tid+1             (segment samples 0..127)
//   c even (>=2)  : row c/2-1,   m = tid+129           (segment samples 128..255)
__global__ __launch_bounds__(128)
void synth_kernel(const float4* __restrict__ SEG,
                  const float*  __restrict__ CW,
                  float* __restrict__ out)
{
    const int c   = blockIdx.x;           // 0..255: samples [128c, 128c+128)
    const int b   = blockIdx.y;
    const int tid = threadIdx.x;

    int row; float m, mask;
    if (c == 0) { row = 0;            m = (float)(tid - 127); mask = 0.f; }
    else if (c & 1) { row = (c - 1) >> 1; m = (float)(tid + 1);   mask = 1.f; }
    else        { row = (c >> 1) - 1; m = (float)(tid + 129); mask = 1.f; }

    const float m2 = m * m * mask;                    // kills quadratic in head
    const float wA = (m - 0.5f) * (1.f / 256.f) * mask;

    const float4* __restrict__ P = SEG + (b * NT + row) * NO;  // uniform base
    const float*  __restrict__ C = CW  + (b * NT + row) * NO;  // uniform base

    float sum0 = 0.f, sum1 = 0.f;
#pragma unroll 4
    for (int o = 0; o < NO; o += 2) {
        // uniform address + __restrict__ no-clobber -> s_load_dwordx4 (SGPRs)
        const float4 p0 = P[o];
        const float4 p1 = P[o + 1];
        const float  c0 = C[o];
        const float  c1 = C[o + 1];
        const float z0 = fmaf(m2, p0.y, fmaf(m, p0.x, c0));  // revolutions
        const float z1 = fmaf(m2, p1.y, fmaf(m, p1.x, c1));
        const float a0 = fmaf(wA, p0.w, p0.z);
        const float a1 = fmaf(wA, p1.w, p1.z);
        sum0 = fmaf(a0, __builtin_amdgcn_sinf(__builtin_amdgcn_fractf(z0)), sum0);
        sum1 = fmaf(a1, __builtin_amdgcn_sinf(__builtin_amdgcn_fractf(z1)), sum1);
    }
    out[b * N_AUDIO + c * 128 + tid] = sum0 + sum1;
}

extern "C" void kernel_launch(void* const* d_in, const int* in_sizes, int n_in,
                              void* d_out, int out_size, void* d_ws, size_t ws_size,
                              hipStream_t stream)
{
    const float* x      = (const float*)d_in[0];
    const float* amp_w  = (const float*)d_in[1];
    const float* amp_b  = (const float*)d_in[2];
    const float* freq_w = (const float*)d_in[3];
    const float* freq_b = (const float*)d_in[4];
    float* out = (float*)d_out;

    float4* SEG = (float4*)d_ws;
    float*  CW  = (float*)((char*)d_ws + (size_t)NB * NT * NO * sizeof(float4));

    prep_kernel<<<dim3(NB * NO), dim3(128), 0, stream>>>(
        x, amp_w, amp_b, freq_w, freq_b, SEG, CW);
    synth_kernel<<<dim3(N_AUDIO / 128, NB), dim3(128), 0, stream>>>(SEG, CW, out);
}

// Round 3
// 84.543 us; speedup vs baseline: 1.0007x; 1.0007x over previous
//
#include <hip/hip_runtime.h>
#include <hip/hip_bf16.h>
#include <math.h>

#define N_AUDIO 32768
#define NB 8
#define NC 128
#define NT 128
#define NO 128

// ws layout:
//   SEG : float4[NB][NT][NO]  (f/2, df/1024, a/128, da/128)  = 2 MiB
//   CW  : float [NB][NT][NO]  ((C_i/2) mod 1, revolutions)   = 512 KiB
// z_rev(m) = CW + m*(f/2) + m^2*(df/1024); audio = sum_o amp'(m)*sin(2*pi*fract(z_rev))

__global__ __launch_bounds__(128)
void prep_kernel(const float* __restrict__ x,
                 const float* __restrict__ amp_w,
                 const float* __restrict__ amp_b,
                 const float* __restrict__ freq_w,
                 const float* __restrict__ freq_b,
                 float4* __restrict__ SEG,
                 float*  __restrict__ CW)
{
    const int bo = blockIdx.x;            // 0..1023
    const int b  = bo >> 7;
    const int o  = bo & 127;
    const int t  = threadIdx.x;           // knot index 0..127

    const float* xp = x + b * (NC * NT) + t;   // x[b, c, t], stride NT per c
    const float* wa = amp_w  + o * NC;
    const float* wf = freq_w + o * NC;

    float va = 0.f, vf = 0.f;
#pragma unroll 8
    for (int c = 0; c < NC; ++c) {
        float xv = xp[c * NT];
        va = fmaf(xv, wa[c], va);
        vf = fmaf(xv, wf[c], vf);
    }
    va += amp_b[o];
    vf += freq_b[o];
    const float sa = 1.f / (1.f + __expf(-va));   // amp knot
    const float sf = 1.f / (1.f + __expf(-vf));   // freq knot

    __shared__ float  fsh[NT];
    __shared__ float  ash[NT];
    __shared__ double psh[NT];
    fsh[t] = sf;
    ash[t] = sa;
    psh[t] = (double)sf;
    __syncthreads();

    // Hillis-Steele inclusive scan (double) over the 128 freq knots
    for (int off = 1; off < NT; off <<= 1) {
        double add = (t >= off) ? psh[t - off] : 0.0;
        double v   = psh[t];
        __syncthreads();
        psh[t] = v + add;
        __syncthreads();
    }
    const double incl = psh[t];
    const double excl = incl - (double)sf;
    // C_i (rev) = 128 * sum_{s<i} f_s + 64 * f_i  (phase/2pi at segment start)
    double Cd = 128.0 * excl + 64.0 * (double)sf;
    Cd -= floor(Cd);                      // mod 1 revolution

    const float df = (t < NT - 1) ? (fsh[t + 1] - sf) : 0.f;
    const float da = (t < NT - 1) ? (ash[t + 1] - sa) : 0.f;

    const int idx = (b * NT + t) * NO + o;   // [b][i][o] layout
    SEG[idx] = make_float4(0.5f * sf,              // m coefficient (rev)
                           df * (1.f / 1024.f),    // m^2 coefficient (rev)
                           sa * (1.f / 128.f),     // amp / 128 (mean folded in)
                           da * (1.f / 128.f));    // damp / 128
    CW[idx]  = (float)Cd;
}

// One WAVE = one segment row = 256 samples (4 samples/lane). Coefficient
// reads amortized 4x per sample vs 1-sample/thread, and C packed as float4
// reads: DS-pipe cost/sample drops ~6x (the R0 bottleneck: ~2280 DS
// cyc/wave for 64 samples; now ~1920 for 256 samples).
//
// Tasks per batch: 0..127 = row r covering samples [256r+128, 256r+384)
// with m = s+1 (s = lane + 64*jj); task 128 = clipped head: row 0, mask 0,
// m = s-127, samples [0,128) only. Row 127 stores only s<128 (js<32768).
__global__ __launch_bounds__(256)
void synth_kernel(const float4* __restrict__ SEG,
                  const float*  __restrict__ CW,
                  float* __restrict__ out)
{
    const int b    = blockIdx.y;
    const int tid  = threadIdx.x;
    const int w    = tid >> 6;            // wave 0..3
    const int l    = tid & 63;
    const int task = blockIdx.x * 4 + w;  // 0..131 (129..131 idle)

    __shared__ __align__(16) float4 sP[4][NO];
    __shared__ __align__(16) float  sC[4][NO];

    const int isHead = (task >= 128) ? 1 : 0;
    const int row    = isHead ? 0 : task;
    const int base   = (b * NT + row) * NO;

    // each wave stages its own row: coalesced 16B/lane float4 loads
    sP[w][l]      = SEG[base + l];
    sP[w][l + 64] = SEG[base + l + 64];
    sC[w][l]      = CW[base + l];
    sC[w][l + 64] = CW[base + l + 64];
    __syncthreads();                      // ordering fence (all waves present)

    if (task > 128) return;

    const float mask  = isHead ? 0.f : 1.f;
    const float mofs  = isHead ? -127.f : 1.f;
    const int   jbase = isHead ? 0 : 256 * row + 128;

    float mm[4], m2[4], wA[4];
#pragma unroll
    for (int jj = 0; jj < 4; ++jj) {
        const float m = (float)(l + 64 * jj) + mofs;
        mm[jj] = m;
        m2[jj] = m * m * mask;                       // kills quadratic in head
        wA[jj] = (m - 0.5f) * (1.f / 256.f) * mask;  // amp-interp weight
    }

    float accE[4] = {0.f, 0.f, 0.f, 0.f};   // even oscillators
    float accO[4] = {0.f, 0.f, 0.f, 0.f};   // odd oscillators

    const float4* __restrict__ P = sP[w];
    const float*  __restrict__ C = sC[w];

#pragma unroll 4
    for (int o = 0; o < NO; o += 4) {
        // broadcast LDS reads (same addr across wave): conflict-free
        const float4 p0 = P[o + 0];
        const float4 p1 = P[o + 1];
        const float4 p2 = P[o + 2];
        const float4 p3 = P[o + 3];
        const float4 c4 = *reinterpret_cast<const float4*>(&C[o]);
#pragma unroll
        for (int jj = 0; jj < 4; ++jj) {
            const float z0 = fmaf(m2[jj], p0.y, fmaf(mm[jj], p0.x, c4.x));
            const float z1 = fmaf(m2[jj], p1.y, fmaf(mm[jj], p1.x, c4.y));
            const float z2 = fmaf(m2[jj], p2.y, fmaf(mm[jj], p2.x, c4.z));
            const float z3 = fmaf(m2[jj], p3.y, fmaf(mm[jj], p3.x, c4.w));
            const float a0 = fmaf(wA[jj], p0.w, p0.z);
            const float a1 = fmaf(wA[jj], p1.w, p1.z);
            const float a2 = fmaf(wA[jj], p2.w, p2.z);
            const float a3 = fmaf(wA[jj], p3.w, p3.z);
            accE[jj] = fmaf(a0, __builtin_amdgcn_sinf(__builtin_amdgcn_fractf(z0)), accE[jj]);
            accO[jj] = fmaf(a1, __builtin_amdgcn_sinf(__builtin_amdgcn_fractf(z1)), accO[jj]);
            accE[jj] = fmaf(a2, __builtin_amdgcn_sinf(__builtin_amdgcn_fractf(z2)), accE[jj]);
            accO[jj] = fmaf(a3, __builtin_amdgcn_sinf(__builtin_amdgcn_fractf(z3)), accO[jj]);
        }
    }

#pragma unroll
    for (int jj = 0; jj < 4; ++jj) {
        const int s  = l + 64 * jj;
        const int js = jbase + s;
        const bool valid = isHead ? (s < 128) : (js < N_AUDIO);
        if (valid) out[b * N_AUDIO + js] = accE[jj] + accO[jj];
    }
}

extern "C" void kernel_launch(void* const* d_in, const int* in_sizes, int n_in,
                              void* d_out, int out_size, void* d_ws, size_t ws_size,
                              hipStream_t stream)
{
    const float* x      = (const float*)d_in[0];
    const float* amp_w  = (const float*)d_in[1];
    const float* amp_b  = (const float*)d_in[2];
    const float* freq_w = (const float*)d_in[3];
    const float* freq_b = (const float*)d_in[4];
    float* out = (float*)d_out;

    float4* SEG = (float4*)d_ws;
    float*  CW  = (float*)((char*)d_ws + (size_t)NB * NT * NO * sizeof(float4));

    prep_kernel<<<dim3(NB * NO), dim3(128), 0, stream>>>(
        x, amp_w, amp_b, freq_w, freq_b, SEG, CW);
    // 129 tasks/batch (128 rows + head), 4 waves/block -> 33 blocks x-dim
    synth_kernel<<<dim3(33, NB), dim3(256), 0, stream>>>(SEG, CW, out);
}